// Round 11
// baseline (719.440 us; speedup 1.0000x reference)
//
#include <hip/hip_runtime.h>
#include <math.h>

#define TOPK 7
// dims (fixed by problem): L=S=2048, B=8, D=1024, H=16, E=64

typedef __attribute__((ext_vector_type(8))) short bf16x8;
typedef __attribute__((ext_vector_type(4))) float f32x4;

// ---------------------------------------------------------------------------
// async global->LDS, 16B per lane (wave-uniform LDS base + lane*16)
// ---------------------------------------------------------------------------
__device__ __forceinline__ void glds16(const ushort* g, ushort* l)
{
    __builtin_amdgcn_global_load_lds(
        (const __attribute__((address_space(1))) void*)g,
        (__attribute__((address_space(3))) void*)l, 16, 0, 0);
}

// ---------------------------------------------------------------------------
// fp32 -> (hi,lo) bf16 split, RN-even via bit ops. n4 = n/4.
// ---------------------------------------------------------------------------
__device__ __forceinline__ void split1(float x, ushort& h, ushort& lo)
{
    union U { float f; unsigned u; };
    U a; a.f = x;
    unsigned r = (a.u + 0x7FFFu + ((a.u >> 16) & 1u)) >> 16;
    h = (ushort)r;
    U b; b.u = r << 16;
    U d; d.f = x - b.f;
    unsigned r2 = (d.u + 0x7FFFu + ((d.u >> 16) & 1u)) >> 16;
    lo = (ushort)r2;
}

__global__ __launch_bounds__(256)
void split_f32(const float* __restrict__ x, ushort* __restrict__ hi,
               ushort* __restrict__ lo, int n4)
{
    for (int i = blockIdx.x * 256 + threadIdx.x; i < n4; i += gridDim.x * 256) {
        float4 v = ((const float4*)x)[i];
        ushort4 h, lw;
        split1(v.x, h.x, lw.x);
        split1(v.y, h.y, lw.y);
        split1(v.z, h.z, lw.z);
        split1(v.w, h.w, lw.w);
        ((ushort4*)hi)[i] = h;
        ((ushort4*)lo)[i] = lw;
    }
}

// ---------------------------------------------------------------------------
// fused 4x weight split (one launch instead of four).
// ---------------------------------------------------------------------------
__global__ __launch_bounds__(256)
void wsplit4(const float* __restrict__ w0, const float* __restrict__ w1,
             const float* __restrict__ w2, const float* __restrict__ w3,
             ushort* __restrict__ o0, ushort* __restrict__ o1,
             ushort* __restrict__ o2, ushort* __restrict__ o3)
{
    const int m = blockIdx.x >> 10;
    const int lb = blockIdx.x & 1023;
    const float* src = (m == 0) ? w0 : (m == 1) ? w1 : (m == 2) ? w2 : w3;
    ushort* hi = (m == 0) ? o0 : (m == 1) ? o1 : (m == 2) ? o2 : o3;
    ushort* lo = hi + 1048576;
    const int n4 = 262144;   // 1024*1024/4
    for (int i = lb * 256 + threadIdx.x; i < n4; i += 1024 * 256) {
        float4 v = ((const float4*)src)[i];
        ushort4 h, lw;
        split1(v.x, h.x, lw.x);
        split1(v.y, h.y, lw.y);
        split1(v.z, h.z, lw.z);
        split1(v.w, h.w, lw.w);
        ((ushort4*)hi)[i] = h;
        ((ushort4*)lo)[i] = lw;
    }
}

// ---------------------------------------------------------------------------
// split-bf16 NT GEMM: C[M,1024] = A[M,1024]*B[1024,1024]^T + bias
// A,B given as (hi,lo) bf16 pairs. C fp32.
//
// ROUND-11 geometry: 128x128 tile, BK=32, 256 thr (4 waves as 2Mx2N;
// wave tile 64x64 = 4x4 frags). LDS = 2 x 32KB double buffer = 64KB/block
// -> 2 BLOCKS/CU (grid 1024 = 4/CU total). Rationale: at 256^2 the grid
// was exactly 1 block/CU, so every barrier stalled the whole CU (41%
// MfmaUtil); with 2 independent resident blocks, one block's MFMA phase
// covers the other's barrier/vmcnt drain (m114 overlap mechanism).
// 3 MFMAs per frag-pair: Ah*Bh + Ah*Bl + Al*Bh. Per-ELEMENT accumulation
// order is IDENTICAL to rounds 6-10 (same K sequence, same MFMA shape)
// -> absmax must stay bit-exact at 4.88e-4.
// Schedule (3 phases, stage-after-last-reader):
//   P0: read B frags + A(i=0,1); 24 MFMAs; barrier
//   P1: stage B(t+2)->cb [B dead after P0]; read A(i=2,3); 24 MFMAs; barrier
//   P2: stage A(t+2)->cb [A dead after P1]; vmcnt(8) [retires tile t+1,
//       keeps t+2's 8 in flight -- T4]; barrier
// ---------------------------------------------------------------------------
template<bool TRANSP>
__global__ __launch_bounds__(256, 2)
void gemm_split(const ushort* __restrict__ Ah, const ushort* __restrict__ Al,
                const ushort* __restrict__ Bh, const ushort* __restrict__ Bl,
                const float* __restrict__ bias, float* __restrict__ C)
{
    __shared__ ushort lds[32768];   // 2 buffers x 32KB = 64KB
    const int tid = threadIdx.x;
    const int w = tid >> 6, l = tid & 63;     // 4 waves

    // T1 swizzle: ord%8 == XCD; nwg divisible by 8.
    const int ord = blockIdx.y * gridDim.x + blockIdx.x;
    const int cpx = (gridDim.x * gridDim.y) >> 3;
    const int swzb = (ord & 7) * cpx + (ord >> 3);
    const int bx = swzb & 7;         // gridDim.x == 8 (N tiles of 128)
    const int by = swzb >> 3;        // M tile

    const int wm = w >> 1, wn = w & 1;        // 2M x 2N waves
    const int lr = l & 15, kgr = l >> 4;

    // staging: 32 pieces (comp{Ah,Al,Bh,Bl} x kg[0,4) x rblk[0,2)), 1KB each.
    // wave w, slot t in [0,8): comp = t>>1, rblk = t&1, kg = w.
    const ushort* gb[8]; size_t go[8]; int lof[8];
#pragma unroll
    for (int t = 0; t < 8; ++t) {
        int comp = t >> 1;
        int rblk = t & 1;
        int kg = w;
        int row0 = ((comp < 2) ? by : bx) * 128 + rblk * 64;
        gb[t] = (comp == 0) ? Ah : (comp == 1) ? Al : (comp == 2) ? Bh : Bl;
        go[t] = (size_t)(row0 + l) * 1024 + kg * 8;
        lof[t] = comp * 4096 + kg * 1024 + rblk * 512;   // ushort units
    }

    f32x4 acc[4][4];
#pragma unroll
    for (int i = 0; i < 4; ++i)
#pragma unroll
        for (int j = 0; j < 4; ++j) acc[i][j] = (f32x4){0.f, 0.f, 0.f, 0.f};

#define STAGE_A(bufbase_, k0_) do { \
    const int _bb = (bufbase_); const int _kk = (k0_); \
    _Pragma("unroll") \
    for (int st = 0; st < 4; ++st) \
        glds16(gb[st] + go[st] + _kk, &lds[_bb + lof[st]]); \
} while (0)

#define STAGE_B(bufbase_, k0_) do { \
    const int _bb = (bufbase_); const int _kk = (k0_); \
    _Pragma("unroll") \
    for (int st = 4; st < 8; ++st) \
        glds16(gb[st] + go[st] + _kk, &lds[_bb + lof[st]]); \
} while (0)

#define COMPUTE2(i0_) do { \
    _Pragma("unroll") \
    for (int ii = 0; ii < 2; ++ii) { \
        const int i = (i0_) + ii; \
        const int ra = wm * 64 + i * 16 + lr; \
        bf16x8 fah = *(const bf16x8*)&lb[       kgr * 1024 + ra * 8]; \
        bf16x8 fal = *(const bf16x8*)&lb[4096 + kgr * 1024 + ra * 8]; \
        __builtin_amdgcn_s_setprio(1); \
        _Pragma("unroll") \
        for (int j = 0; j < 4; ++j) \
            acc[i][j] = __builtin_amdgcn_mfma_f32_16x16x32_bf16(fah, fbh[j], acc[i][j], 0, 0, 0); \
        _Pragma("unroll") \
        for (int j = 0; j < 4; ++j) \
            acc[i][j] = __builtin_amdgcn_mfma_f32_16x16x32_bf16(fah, fbl[j], acc[i][j], 0, 0, 0); \
        _Pragma("unroll") \
        for (int j = 0; j < 4; ++j) \
            acc[i][j] = __builtin_amdgcn_mfma_f32_16x16x32_bf16(fal, fbh[j], acc[i][j], 0, 0, 0); \
        __builtin_amdgcn_s_setprio(0); \
    } \
} while (0)

    // prologue: tile 0 -> buf0, tile 1 -> buf1 (16 loads; oldest 8 = tile 0)
    STAGE_B(0, 0);      STAGE_A(0, 0);
    STAGE_B(16384, 32); STAGE_A(16384, 32);
    asm volatile("s_waitcnt vmcnt(8)" ::: "memory");   // tile 0 resident
    __builtin_amdgcn_s_barrier();

#pragma unroll 2
    for (int t = 0; t < 32; ++t) {
        const int cb = (t & 1) * 16384;
        const ushort* lb = &lds[cb];
        const bool pre = (t < 30);
        const int kn = (t + 2) * 32;

        // ---- P0: B frags (8 reads) + compute i=0,1
        bf16x8 fbh[4], fbl[4];
#pragma unroll
        for (int j = 0; j < 4; ++j) {
            int rb = wn * 64 + j * 16 + lr;
            fbh[j] = *(const bf16x8*)&lb[8192  + kgr * 1024 + rb * 8];
            fbl[j] = *(const bf16x8*)&lb[12288 + kgr * 1024 + rb * 8];
        }
        COMPUTE2(0);
        __builtin_amdgcn_s_barrier();

        // ---- P1: stage B(t+2) into freed B-region; compute i=2,3
        if (pre) STAGE_B(cb, kn);
        COMPUTE2(2);
        __builtin_amdgcn_s_barrier();

        // ---- P2: stage A(t+2) [A dead after P1's reads]; counted vmcnt
        if (pre) {
            STAGE_A(cb, kn);
            asm volatile("s_waitcnt vmcnt(8)" ::: "memory");
        } else {
            asm volatile("s_waitcnt vmcnt(0)" ::: "memory");
        }
        __builtin_amdgcn_s_barrier();
    }
#undef STAGE_A
#undef STAGE_B
#undef COMPUTE2

    if (!TRANSP) {
        // epilogue: C/D layout col = lane&15, row = (lane>>4)*4+reg [m89]
#pragma unroll
        for (int j = 0; j < 4; ++j) {
            int col = bx * 128 + wn * 64 + j * 16 + lr;
            float bb = bias[col];
#pragma unroll
            for (int i = 0; i < 4; ++i) {
                int row0 = by * 128 + wm * 64 + i * 16 + kgr * 4;
#pragma unroll
                for (int reg = 0; reg < 4; ++reg)
                    C[(size_t)(row0 + reg) * 1024 + col] = acc[i][j][reg] + bb;
            }
        }
    } else {
        // transposed epilogue: write Qa[bh][e][t]. Tile: rows R=by*128+rl
        // (t=by*16+(rl>>3), b=rl&7), cols Cc=bx*128+cl (h=bx*2+(cl>>6),
        // e=cl&63). Single 64KB pass (128x128 f32 fills lds exactly).
        // XOR swizzle both sides: cs = cl ^ (rl & 31).
        float* lf = (float*)lds;
#pragma unroll
        for (int j = 0; j < 4; ++j) {
            int col = bx * 128 + wn * 64 + j * 16 + lr;
            float bb = bias[col];
            int cl = wn * 64 + j * 16 + lr;
#pragma unroll
            for (int i = 0; i < 4; ++i) {
                int rbase = wm * 64 + i * 16 + kgr * 4;
#pragma unroll
                for (int reg = 0; reg < 4; ++reg) {
                    int rl = rbase + reg;
                    lf[rl * 128 + (cl ^ (rl & 31))] = acc[i][j][reg] + bb;
                }
            }
        }
        __syncthreads();
#pragma unroll
        for (int it = 0; it < 16; ++it) {
            int vi = it * 256 + tid;          // [0,4096)
            int tq4 = vi & 3;
            int e   = (vi >> 2) & 63;
            int hll = (vi >> 8) & 1;
            int b   = vi >> 9;
            float4 v;
#pragma unroll
            for (int k = 0; k < 4; ++k) {
                int rl = (tq4 * 4 + k) * 8 + b;
                int cl = hll * 64 + e;
                ((float*)&v)[k] = lf[rl * 128 + (cl ^ (rl & 31))];
            }
            int bh = b * 16 + bx * 2 + hll;
            ((float4*)C)[(size_t)(bh * 64 + e) * 512 + by * 4 + tq4] = v;
        }
    }
}

// ---------------------------------------------------------------------------
// transpose (t,b,d) -> [bh][e][t]   (fallback path only)
// ---------------------------------------------------------------------------
__global__ __launch_bounds__(256)
void transpose_bhet(const float* __restrict__ src, float* __restrict__ dst)
{
    __shared__ float tile[64][129];
    const int tid = threadIdx.x;
    const int bh = blockIdx.x;
    const int b = bh >> 4, h = bh & 15;
    const int t0 = blockIdx.y * 128;
    const float* sp = src + (size_t)(t0 * 8 + b) * 1024 + h * 64;
#pragma unroll
    for (int i = 0; i < 8; ++i) {
        int idx = i * 256 + tid;
        int t = idx >> 4;
        int e4 = (idx & 15) * 4;
        float4 v = *(const float4*)(sp + (size_t)t * 8192 + e4);
        tile[e4 + 0][t] = v.x; tile[e4 + 1][t] = v.y; tile[e4 + 2][t] = v.z; tile[e4 + 3][t] = v.w;
    }
    __syncthreads();
    float* dp = dst + (size_t)bh * 64 * 2048 + t0;
#pragma unroll
    for (int i = 0; i < 8; ++i) {
        int idx = i * 256 + tid;
        int e = idx >> 5;
        int t4 = (idx & 31) * 4;
        float4 o;
        o.x = tile[e][t4]; o.y = tile[e][t4 + 1]; o.z = tile[e][t4 + 2]; o.w = tile[e][t4 + 3];
        *(float4*)(dp + (size_t)e * 2048 + t4) = o;
    }
}

// ---------------------------------------------------------------------------
__device__ __forceinline__ float2 cadd(float2 a, float2 b){ return make_float2(a.x+b.x, a.y+b.y); }
__device__ __forceinline__ float2 csub(float2 a, float2 b){ return make_float2(a.x-b.x, a.y-b.y); }
__device__ __forceinline__ float2 cmul(float2 a, float2 b){ return make_float2(a.x*b.x - a.y*b.y, a.x*b.y + a.y*b.x); }

// ---------------------------------------------------------------------------
// XOR bank-swizzle for the FFT LDS buffers (bijective on [0,2048)).
// ---------------------------------------------------------------------------
__device__ __forceinline__ int swz(int i) { return i ^ ((i >> 4) & 15); }

// ---------------------------------------------------------------------------
// In-LDS 2048-pt complex FFT: 3 radix-8 Stockham stages + 1 twiddle-free
// radix-4 = 4 LDS passes. (See round 9 derivation.)
// ---------------------------------------------------------------------------
__device__ float2* fft2048(float2* x, float2* y, const float2* tw, int tid)
{
#pragma unroll 1
    for (int st = 0; st < 3; ++st) {
        const int s = 1 << (3 * st);   // 1, 8, 64
        const int u = tid;             // 256 butterflies, 1/thread
        const int q = u & (s - 1);
        const int ps = u - q;
        float2 a = x[swz(u)],        e = x[swz(u + 256)];
        float2 b = x[swz(u + 512)],  f = x[swz(u + 768)];
        float2 c = x[swz(u + 1024)], g = x[swz(u + 1280)];
        float2 d = x[swz(u + 1536)], h = x[swz(u + 1792)];
        float2 t0 = cadd(a, c), t1 = csub(a, c);
        float2 t2 = cadd(b, d), tb = csub(b, d);
        float2 t3 = make_float2(tb.y, -tb.x);
        float2 A0 = cadd(t0, t2);
        float2 A1 = cmul(cadd(t1, t3), tw[ps]);
        float2 A2 = cmul(csub(t0, t2), tw[2 * ps]);
        float2 A3 = cmul(csub(t1, t3), tw[3 * ps]);
        float2 s0 = cadd(e, g), s1 = csub(e, g);
        float2 s2 = cadd(f, h), sb = csub(f, h);
        float2 s3 = make_float2(sb.y, -sb.x);
        float2 B0 = cadd(s0, s2);
        float2 B1 = cmul(cadd(s1, s3), tw[ps + 256]);
        float2 B2 = cmul(csub(s0, s2), tw[2 * ps + 512]);
        const int i3 = 3 * ps + 768;
        float2 w3b = (i3 < 1024) ? tw[i3]
                   : make_float2(-tw[i3 - 1024].x, -tw[i3 - 1024].y);
        float2 B3 = cmul(csub(s1, s3), w3b);
        float2 w4 = tw[4 * ps];
        const int o = 8 * ps + q;
        y[swz(o)]         = cadd(A0, B0);
        y[swz(o + s)]     = cadd(A1, B1);
        y[swz(o + 2 * s)] = cadd(A2, B2);
        y[swz(o + 3 * s)] = cadd(A3, B3);
        y[swz(o + 4 * s)] = cmul(csub(A0, B0), w4);
        y[swz(o + 5 * s)] = cmul(csub(A1, B1), w4);
        y[swz(o + 6 * s)] = cmul(csub(A2, B2), w4);
        y[swz(o + 7 * s)] = cmul(csub(A3, B3), w4);
        __syncthreads();
        float2* tsw = x; x = y; y = tsw;
    }
    // final radix-4, s=512: ps==0 -> twiddle-free
#pragma unroll
    for (int ui = 0; ui < 2; ++ui) {
        const int u = ui * 256 + tid;   // [0,512)
        float2 a = x[swz(u)],        b = x[swz(u + 512)];
        float2 c = x[swz(u + 1024)], d = x[swz(u + 1536)];
        float2 t0 = cadd(a, c), t1 = csub(a, c);
        float2 t2 = cadd(b, d), tb = csub(b, d);
        float2 t3 = make_float2(tb.y, -tb.x);
        y[swz(u)]        = cadd(t0, t2);
        y[swz(u + 512)]  = cadd(t1, t3);
        y[swz(u + 1024)] = csub(t0, t2);
        y[swz(u + 1536)] = csub(t1, t3);
    }
    __syncthreads();
    return y;
}

// ---------------------------------------------------------------------------
// corr_fwd: grid (128 bh, 8 eg). FFT 8 packed (Q,K) rows, accumulate partial
// S[f] = sum_e Qf*conj(Kf) in registers, write to Spart[bh][eg][1025].
// ---------------------------------------------------------------------------
__global__ __launch_bounds__(256)
void corr_fwd(const float* __restrict__ Qa, const float* __restrict__ Ka,
              float2* __restrict__ Spart)
{
    __shared__ float2 za[2048];
    __shared__ float2 zb[2048];
    __shared__ float2 tw[1024];
    const int tid = threadIdx.x;
    const int bh = blockIdx.x;
    const int eg = blockIdx.y;

#pragma unroll
    for (int r = 0; r < 4; ++r) {
        int u = tid + 256 * r;
        float sn, cs;
        sincospif((float)u * (1.0f / 1024.0f), &sn, &cs);
        tw[u] = make_float2(cs, -sn);
    }

    float2 sacc[4];
#pragma unroll
    for (int r = 0; r < 4; ++r) sacc[r] = make_float2(0.f, 0.f);
    float2 sacc1024 = make_float2(0.f, 0.f);

    const float* q0 = Qa + ((size_t)bh * 64 + eg * 8) * 2048;
    const float* k0 = Ka + ((size_t)bh * 64 + eg * 8) * 2048;

    for (int e = 0; e < 8; ++e) {
        const float* qr = q0 + (size_t)e * 2048;
        const float* kr = k0 + (size_t)e * 2048;
        for (int t = tid; t < 2048; t += 256)
            za[swz(t)] = make_float2(qr[t], kr[t]);
        __syncthreads();

        float2* res = fft2048(za, zb, tw, tid);

#pragma unroll
        for (int r = 0; r < 4; ++r) {
            int f = tid + 256 * r;
            float2 A  = res[swz(f)];
            float2 Bc = res[swz((2048 - f) & 2047)];
            float Ur = A.x + Bc.x, Ui = A.y - Bc.y;
            float Vr = A.x - Bc.x, Vi = -A.y - Bc.y;
            sacc[r].x += 0.25f * (-(Ur * Vi + Ui * Vr));
            sacc[r].y += 0.25f * ( Ur * Vr - Ui * Vi );
        }
        if (tid == 0) {
            float2 A = res[swz(1024)];
            float Ur = 2.f * A.x;
            float Vi = -2.f * A.y;
            sacc1024.x += 0.25f * (-(Ur * Vi));
            sacc1024.y += 0.25f * 0.f;
        }
        __syncthreads();
    }
    float2* sp = Spart + ((size_t)bh * 8 + eg) * 1025;
#pragma unroll
    for (int r = 0; r < 4; ++r) sp[tid + 256 * r] = sacc[r];
    if (tid == 0) sp[1024] = sacc1024;
}

// ---------------------------------------------------------------------------
// corr_inv_topk: sum 8 partials, inverse FFT (conj trick), top-7 + softmax.
// ---------------------------------------------------------------------------
__global__ __launch_bounds__(256)
void corr_inv_topk(const float2* __restrict__ Spart,
                   int* __restrict__ taus, float* __restrict__ wout)
{
    __shared__ float2 za[2048];
    __shared__ float2 zb[2048];
    __shared__ float2 tw[1024];
    __shared__ float2 Sh[1025];
    __shared__ float  redv[256];
    __shared__ int    redi[256];
    __shared__ float  sc[TOPK];
    __shared__ int    si[TOPK];

    const int tid = threadIdx.x;
    const int bh = blockIdx.x;

#pragma unroll
    for (int r = 0; r < 4; ++r) {
        int u = tid + 256 * r;
        float sn, cs;
        sincospif((float)u * (1.0f / 1024.0f), &sn, &cs);
        tw[u] = make_float2(cs, -sn);
    }

    const float2* sp0 = Spart + (size_t)bh * 8 * 1025;
    for (int f = tid; f < 1025; f += 256) {
        float2 s = make_float2(0.f, 0.f);
#pragma unroll
        for (int g = 0; g < 8; ++g) {
            float2 v = sp0[(size_t)g * 1025 + f];
            s.x += v.x; s.y += v.y;
        }
        Sh[f] = s;
    }
    __syncthreads();
    for (int f = tid; f < 2048; f += 256) {
        float2 v = (f <= 1024) ? make_float2(Sh[f].x, -Sh[f].y) : Sh[2048 - f];
        za[swz(f)] = v;
    }
    __syncthreads();

    float2* res = fft2048(za, zb, tw, tid);

    for (int k = 0; k < TOPK; ++k) {
        float bvv = -INFINITY; int bii = 0;
        for (int t = tid; t < 2048; t += 256) {
            float v = res[swz(t)].x;
            if (v > bvv) { bvv = v; bii = t; }
        }
        redv[tid] = bvv; redi[tid] = bii;
        __syncthreads();
        for (int off = 128; off > 0; off >>= 1) {
            if (tid < off) {
                float ov = redv[tid + off]; int oi = redi[tid + off];
                if (ov > redv[tid] || (ov == redv[tid] && oi < redi[tid])) { redv[tid] = ov; redi[tid] = oi; }
            }
            __syncthreads();
        }
        if (tid == 0) { sc[k] = redv[0]; si[k] = redi[0]; res[swz(redi[0])].x = -INFINITY; }
        __syncthreads();
    }
    if (tid == 0) {
        const float scale = 1.0f / (2048.0f * 64.0f);
        float m = sc[0] * scale;
        float ex[TOPK]; float ssum = 0.f;
        for (int k = 0; k < TOPK; ++k) { ex[k] = expf(sc[k] * scale - m); ssum += ex[k]; }
        for (int k = 0; k < TOPK; ++k) {
            taus[bh * TOPK + k] = si[k];
            wout[bh * TOPK + k] = ex[k] / ssum;
        }
    }
}

// ---------------------------------------------------------------------------
// agg = (1/7) * sum_k w[bh][k] * V[(t+tau_k)%L, b, :]; emits (hi,lo) bf16
// directly (feeds the split-GEMM output projection).
// ---------------------------------------------------------------------------
__global__ __launch_bounds__(256)
void agg_gather(const float* __restrict__ Vp, const int* __restrict__ taus,
                const float* __restrict__ w, ushort* __restrict__ ah,
                ushort* __restrict__ al)
{
    const int tid = threadIdx.x;
    const int bh = blockIdx.x;
    const int b = bh >> 4, h = bh & 15;
    const int t0 = blockIdx.y * 256;
    __shared__ int   stau[TOPK];
    __shared__ float sw[TOPK];
    if (tid < TOPK) { stau[tid] = taus[bh * TOPK + tid]; sw[tid] = w[bh * TOPK + tid] * (1.0f / TOPK); }
    __syncthreads();
    const float* vb = Vp + (size_t)b * 1024 + h * 64;
    ushort* ahb = ah + (size_t)b * 1024 + h * 64;
    ushort* alb = al + (size_t)b * 1024 + h * 64;
#pragma unroll
    for (int i = 0; i < 16; ++i) {
        int idx = i * 256 + tid;
        int t  = t0 + (idx >> 4);
        int e4 = (idx & 15) * 4;
        float a0 = 0.f, a1 = 0.f, a2 = 0.f, a3 = 0.f;
#pragma unroll
        for (int k = 0; k < TOPK; ++k) {
            int ts = (t + stau[k]) & 2047;
            float4 v = *(const float4*)(vb + (size_t)ts * 8192 + e4);
            a0 = fmaf(sw[k], v.x, a0); a1 = fmaf(sw[k], v.y, a1);
            a2 = fmaf(sw[k], v.z, a2); a3 = fmaf(sw[k], v.w, a3);
        }
        ushort4 hh, ll;
        split1(a0, hh.x, ll.x); split1(a1, hh.y, ll.y);
        split1(a2, hh.z, ll.z); split1(a3, hh.w, ll.w);
        *(ushort4*)(ahb + (size_t)t * 8192 + e4) = hh;
        *(ushort4*)(alb + (size_t)t * 8192 + e4) = ll;
    }
}

// ---------------------------------------------------------------------------
extern "C" void kernel_launch(void* const* d_in, const int* in_sizes, int n_in,
                              void* d_out, int out_size, void* d_ws, size_t ws_size,
                              hipStream_t stream)
{
    (void)in_sizes; (void)n_in; (void)out_size;
    const float* query = (const float*)d_in[0];
    const float* key   = (const float*)d_in[1];
    const float* value = (const float*)d_in[2];
    const float* Wq = (const float*)d_in[3];
    const float* bq = (const float*)d_in[4];
    const float* Wk = (const float*)d_in[5];
    const float* bk = (const float*)d_in[6];
    const float* Wv = (const float*)d_in[7];
    const float* bv = (const float*)d_in[8];
    const float* Wo = (const float*)d_in[9];
    const float* bo = (const float*)d_in[10];
    float* out = (float*)d_out;

    const size_t NEL  = (size_t)16777216;   // 16384*1024
    const size_t HEL  = NEL / 2;            // value half
    const size_t WEL  = (size_t)1048576;    // 1024*1024
    const size_t SLOTB = (size_t)64 * 1024 * 1024;
    const size_t MB = (size_t)1024 * 1024;

    char* ws = (char*)d_ws;
    float*  s1 = (float*)ws;                 // fp32 proj outputs (Vp)
    char*   s2 = ws + SLOTB;                 // X(q) -> X(k) -> X(v) -> Spart
    char*   s3 = ws + 2 * SLOTB;             // Qa -> agg hi/lo
    char*   tail = ws + 3 * SLOTB;           // dtaus/dw + W homes
    int*    dtaus = (int*)tail;
    float*  dw    = (float*)(dtaus + 128 * TOPK);
    const bool big_ws = ws_size >= 3 * SLOTB + (size_t)16 * MB;

    dim3 blk(256);
    dim3 gemm_full(8, 128), gemm_half(8, 64);   // 128x128 tiles
    dim3 tr_grid(128, 16);

    if (big_ws) {
        ushort* wqh = (ushort*)d_out;
        ushort* wkh = (ushort*)(tail + 4 * MB);
        ushort* wvh = (ushort*)(tail + 8 * MB);
        ushort* woh = (ushort*)(tail + 12 * MB);

        // 1. all four weight splits in ONE launch
        wsplit4<<<4096, blk, 0, stream>>>(Wq, Wk, Wv, Wo, wqh, wkh, wvh, woh);
        // 2. query split -> s2 (bf16 hi/lo)
        split_f32<<<2048, blk, 0, stream>>>(query, (ushort*)s2, (ushort*)s2 + NEL, (int)(NEL / 4));
        // 3. Q projection + fused transpose -> Qa in s3
        gemm_split<true><<<gemm_full, blk, 0, stream>>>((ushort*)s2, (ushort*)s2 + NEL,
                                                        wqh, wqh + WEL, bq, (float*)s3);
        // 4. key split -> s2 (query split dead)
        split_f32<<<2048, blk, 0, stream>>>(key, (ushort*)s2, (ushort*)s2 + NEL, (int)(NEL / 4));
        // 5. K projection + fused transpose -> Ka in d_out (Wq home dead)
        float* Ka = (float*)d_out;
        gemm_split<true><<<gemm_full, blk, 0, stream>>>((ushort*)s2, (ushort*)s2 + NEL,
                                                        wkh, wkh + WEL, bk, Ka);
        // 6. value split -> s2 (key split dead)
        split_f32<<<2048, blk, 0, stream>>>(value, (ushort*)s2, (ushort*)s2 + NEL, (int)(NEL / 4));
        // 7. V projection -> s1 (normal layout)
        gemm_split<false><<<gemm_full, blk, 0, stream>>>((ushort*)s2, (ushort*)s2 + NEL,
                                                         wvh, wvh + WEL, bv, s1);
        // 8. correlation forward (Qa=s3, Ka=d_out) -> Spart in s2 (value split dead)
        float2* Spart = (float2*)s2;
        corr_fwd<<<dim3(128, 8), blk, 0, stream>>>((const float*)s3, Ka, Spart);
        // 9. inverse + top-k + softmax
        corr_inv_topk<<<dim3(128), blk, 0, stream>>>(Spart, dtaus, dw);
        // 10. delayed-V aggregation -> (hi,lo) in s3 (Qa dead)
        agg_gather<<<dim3(128, 8), blk, 0, stream>>>(s1, dtaus, dw,
                                                     (ushort*)s3, (ushort*)s3 + NEL);
        // 11. output projection -> d_out
        gemm_split<false><<<gemm_full, blk, 0, stream>>>((ushort*)s3, (ushort*)s3 + NEL,
                                                         woh, woh + WEL, bo, out);
    } else {
        // fallback: scattered W splits, two-half V path, separate transposes
        split_f32<<<1024, blk, 0, stream>>>(Wq, (ushort*)s3, (ushort*)s3 + WEL, (int)(WEL / 4));
        split_f32<<<2048, blk, 0, stream>>>(query, (ushort*)s2, (ushort*)s2 + NEL, (int)(NEL / 4));
        gemm_split<false><<<gemm_full, blk, 0, stream>>>((ushort*)s2, (ushort*)s2 + NEL,
                                                         (ushort*)s3, (ushort*)s3 + WEL, bq, s1);
        transpose_bhet<<<tr_grid, blk, 0, stream>>>(s1, (float*)s2);
        ushort* wkh = (ushort*)d_out;
        split_f32<<<1024, blk, 0, stream>>>(Wk, wkh, wkh + WEL, (int)(WEL / 4));
        split_f32<<<2048, blk, 0, stream>>>(key, (ushort*)s3, (ushort*)s3 + NEL, (int)(NEL / 4));
        gemm_split<false><<<gemm_full, blk, 0, stream>>>((ushort*)s3, (ushort*)s3 + NEL,
                                                         wkh, wkh + WEL, bk, s1);
        transpose_bhet<<<tr_grid, blk, 0, stream>>>(s1, (float*)s3);
        ushort* wvh = (ushort*)((char*)d_out + (size_t)32 * MB);
        split_f32<<<1024, blk, 0, stream>>>(Wv, wvh, wvh + WEL, (int)(WEL / 4));
        ushort* vsp = (ushort*)d_out;
        for (int hhalf = 0; hhalf < 2; ++hhalf) {
            split_f32<<<2048, blk, 0, stream>>>(value + hhalf * HEL, vsp, vsp + HEL, (int)(HEL / 4));
            gemm_split<false><<<gemm_half, blk, 0, stream>>>(vsp, vsp + HEL, wvh, wvh + WEL,
                                                             bv, s1 + hhalf * HEL);
        }
        float2* Spart = (float2*)d_out;
        corr_fwd<<<dim3(128, 8), blk, 0, stream>>>((const float*)s2, (const float*)s3, Spart);
        corr_inv_topk<<<dim3(128), blk, 0, stream>>>(Spart, dtaus, dw);
        agg_gather<<<dim3(128, 8), blk, 0, stream>>>(s1, dtaus, dw,
                                                     (ushort*)s2, (ushort*)s2 + NEL);
        split_f32<<<1024, blk, 0, stream>>>(Wo, (ushort*)s3, (ushort*)s3 + WEL, (int)(WEL / 4));
        gemm_split<false><<<gemm_full, blk, 0, stream>>>((ushort*)s2, (ushort*)s2 + NEL,
                                                         (ushort*)s3, (ushort*)s3 + WEL, bo, out);
    }
}

// Round 12
// 584.110 us; speedup vs baseline: 1.2317x; 1.2317x over previous
//
#include <hip/hip_runtime.h>
#include <math.h>

#define TOPK 7
// dims (fixed by problem): L=S=2048, B=8, D=1024, H=16, E=64

typedef __attribute__((ext_vector_type(8))) short bf16x8;
typedef __attribute__((ext_vector_type(4))) float f32x4;

// ---------------------------------------------------------------------------
// async global->LDS, 16B per lane (wave-uniform LDS base + lane*16)
// ---------------------------------------------------------------------------
__device__ __forceinline__ void glds16(const ushort* g, ushort* l)
{
    __builtin_amdgcn_global_load_lds(
        (const __attribute__((address_space(1))) void*)g,
        (__attribute__((address_space(3))) void*)l, 16, 0, 0);
}

// ---------------------------------------------------------------------------
// fp32 -> (hi,lo) bf16 split, RN-even via bit ops. n4 = n/4.
// ---------------------------------------------------------------------------
__device__ __forceinline__ void split1(float x, ushort& h, ushort& lo)
{
    union U { float f; unsigned u; };
    U a; a.f = x;
    unsigned r = (a.u + 0x7FFFu + ((a.u >> 16) & 1u)) >> 16;
    h = (ushort)r;
    U b; b.u = r << 16;
    U d; d.f = x - b.f;
    unsigned r2 = (d.u + 0x7FFFu + ((d.u >> 16) & 1u)) >> 16;
    lo = (ushort)r2;
}

__global__ __launch_bounds__(256)
void split_f32(const float* __restrict__ x, ushort* __restrict__ hi,
               ushort* __restrict__ lo, int n4)
{
    for (int i = blockIdx.x * 256 + threadIdx.x; i < n4; i += gridDim.x * 256) {
        float4 v = ((const float4*)x)[i];
        ushort4 h, lw;
        split1(v.x, h.x, lw.x);
        split1(v.y, h.y, lw.y);
        split1(v.z, h.z, lw.z);
        split1(v.w, h.w, lw.w);
        ((ushort4*)hi)[i] = h;
        ((ushort4*)lo)[i] = lw;
    }
}

// ---------------------------------------------------------------------------
// fused 4x weight split (one launch instead of four).
// ---------------------------------------------------------------------------
__global__ __launch_bounds__(256)
void wsplit4(const float* __restrict__ w0, const float* __restrict__ w1,
             const float* __restrict__ w2, const float* __restrict__ w3,
             ushort* __restrict__ o0, ushort* __restrict__ o1,
             ushort* __restrict__ o2, ushort* __restrict__ o3)
{
    const int m = blockIdx.x >> 10;
    const int lb = blockIdx.x & 1023;
    const float* src = (m == 0) ? w0 : (m == 1) ? w1 : (m == 2) ? w2 : w3;
    ushort* hi = (m == 0) ? o0 : (m == 1) ? o1 : (m == 2) ? o2 : o3;
    ushort* lo = hi + 1048576;
    const int n4 = 262144;   // 1024*1024/4
    for (int i = lb * 256 + threadIdx.x; i < n4; i += 1024 * 256) {
        float4 v = ((const float4*)src)[i];
        ushort4 h, lw;
        split1(v.x, h.x, lw.x);
        split1(v.y, h.y, lw.y);
        split1(v.z, h.z, lw.z);
        split1(v.w, h.w, lw.w);
        ((ushort4*)hi)[i] = h;
        ((ushort4*)lo)[i] = lw;
    }
}

// ---------------------------------------------------------------------------
// split-bf16 NT GEMM: C[M,1024] = A[M,1024]*B[1024,1024]^T + bias
// A,B given as (hi,lo) bf16 pairs. C fp32.
//
// ROUND-6 geometry+schedule (re-verified local optimum: ~106us, MfmaUtil
// 41.5%): 256x256 tile, BK=32, 512 thr, 4 phases/1 barrier each, counted
// vmcnt(8) (T4), setprio (T5). r11's 128^2/2-block experiment: -40%
// (same 8 waves/CU, worse MFMA:ds ratio, +75% FETCH) -- do not revisit.
//
// TRANSP=true: write DIRECTLY in FFT layout Qa[bh][e][t] via LDS-staged
// transposed epilogue (2 col-half passes; main-loop LDS dead by then).
// ---------------------------------------------------------------------------
template<bool TRANSP>
__global__ __launch_bounds__(512, 2)
void gemm_split(const ushort* __restrict__ Ah, const ushort* __restrict__ Al,
                const ushort* __restrict__ Bh, const ushort* __restrict__ Bl,
                const float* __restrict__ bias, float* __restrict__ C)
{
    __shared__ ushort lds[65536];   // 2 buffers x 64KB = 128KB
    const int tid = threadIdx.x;
    const int w = tid >> 6, l = tid & 63;

    // T1 swizzle: ord%8 == XCD (round-robin dispatch); nwg divisible by 8.
    const int ord = blockIdx.y * gridDim.x + blockIdx.x;
    const int cpx = (gridDim.x * gridDim.y) >> 3;
    const int swzb = (ord & 7) * cpx + (ord >> 3);
    const int bx = swzb & 3;         // gridDim.x == 4 (N tiles of 256)
    const int by = swzb >> 2;        // M tile

    const int wm = w >> 2, wn = w & 3;      // 2M x 4N waves
    const int lr = l & 15, kgr = l >> 4;

    const ushort* gbB[4]; size_t goB[4]; int loB[4];
    const ushort* gbA[4]; size_t goA[4]; int loA[4];
#pragma unroll
    for (int q = 0; q < 4; ++q) {
        int idx = w * 4 + q;
        int cbq = idx >> 4;
        int kg = (idx >> 2) & 3;
        int rblk = idx & 3;            // == q
        gbB[q] = cbq ? Bl : Bh;
        goB[q] = (size_t)(bx * 256 + rblk * 64 + l) * 1024 + kg * 8;
        loB[q] = 16384 + cbq * 8192 + kg * 2048 + rblk * 512;
        gbA[q] = cbq ? Al : Ah;
        goA[q] = (size_t)(by * 256 + rblk * 64 + l) * 1024 + kg * 8;
        loA[q] = cbq * 8192 + kg * 2048 + rblk * 512;
    }

    f32x4 acc[8][4];
#pragma unroll
    for (int i = 0; i < 8; ++i)
#pragma unroll
        for (int j = 0; j < 4; ++j) acc[i][j] = (f32x4){0.f, 0.f, 0.f, 0.f};

#define STAGE_B(bufbase_, k0_) do { \
    const int _bb = (bufbase_); const int _kk = (k0_); \
    _Pragma("unroll") \
    for (int q = 0; q < 4; ++q) \
        glds16(gbB[q] + goB[q] + _kk, &lds[_bb + loB[q]]); \
} while (0)

#define STAGE_A2(bufbase_, k0_, qa_, qb_) do { \
    const int _bb = (bufbase_); const int _kk = (k0_); \
    glds16(gbA[qa_] + goA[qa_] + _kk, &lds[_bb + loA[qa_]]); \
    glds16(gbA[qb_] + goA[qb_] + _kk, &lds[_bb + loA[qb_]]); \
} while (0)

#define COMPUTE2(i0_) do { \
    _Pragma("unroll") \
    for (int ii = 0; ii < 2; ++ii) { \
        const int i = (i0_) + ii; \
        const int ra = wm * 128 + i * 16 + lr; \
        bf16x8 fah = *(const bf16x8*)&lb[       kgr * 2048 + ra * 8]; \
        bf16x8 fal = *(const bf16x8*)&lb[8192 + kgr * 2048 + ra * 8]; \
        __builtin_amdgcn_s_setprio(1); \
        _Pragma("unroll") \
        for (int j = 0; j < 4; ++j) \
            acc[i][j] = __builtin_amdgcn_mfma_f32_16x16x32_bf16(fah, fbh[j], acc[i][j], 0, 0, 0); \
        _Pragma("unroll") \
        for (int j = 0; j < 4; ++j) \
            acc[i][j] = __builtin_amdgcn_mfma_f32_16x16x32_bf16(fah, fbl[j], acc[i][j], 0, 0, 0); \
        _Pragma("unroll") \
        for (int j = 0; j < 4; ++j) \
            acc[i][j] = __builtin_amdgcn_mfma_f32_16x16x32_bf16(fal, fbh[j], acc[i][j], 0, 0, 0); \
        __builtin_amdgcn_s_setprio(0); \
    } \
} while (0)

    // prologue: tile 0 -> buf0, tile 1 -> buf1
    STAGE_B(0, 0);       STAGE_A2(0, 0, 0, 1);       STAGE_A2(0, 0, 2, 3);
    STAGE_B(32768, 32);  STAGE_A2(32768, 32, 0, 1);  STAGE_A2(32768, 32, 2, 3);
    asm volatile("s_waitcnt vmcnt(8)" ::: "memory");   // tile 0 resident
    __builtin_amdgcn_s_barrier();

#pragma unroll 2
    for (int t = 0; t < 32; ++t) {
        const int cb = (t & 1) * 32768;
        const ushort* lb = &lds[cb];
        const bool pre = (t < 30);
        const int kn = (t + 2) * 32;

        // ---- phase 0: B-frags (8 reads) + compute i=0,1
        bf16x8 fbh[4], fbl[4];
#pragma unroll
        for (int j = 0; j < 4; ++j) {
            int rb = wn * 64 + j * 16 + lr;
            fbh[j] = *(const bf16x8*)&lb[16384 + kgr * 2048 + rb * 8];
            fbl[j] = *(const bf16x8*)&lb[24576 + kgr * 2048 + rb * 8];
        }
        COMPUTE2(0);
        __builtin_amdgcn_s_barrier();

        // ---- phase 1: stage B(t+2) into the freed B-region; i=2,3
        if (pre) STAGE_B(cb, kn);
        COMPUTE2(2);
        __builtin_amdgcn_s_barrier();

        // ---- phase 2: stage A rblk0,2; i=4,5
        if (pre) STAGE_A2(cb, kn, 0, 2);
        COMPUTE2(4);
        __builtin_amdgcn_s_barrier();

        // ---- phase 3: i=6,7; then stage A rblk1,3; counted vmcnt
        COMPUTE2(6);
        __builtin_amdgcn_s_barrier();
        if (pre) {
            STAGE_A2(cb, kn, 1, 3);
            asm volatile("s_waitcnt vmcnt(8)" ::: "memory");
        } else {
            asm volatile("s_waitcnt vmcnt(0)" ::: "memory");
        }
        __builtin_amdgcn_s_barrier();
    }
#undef STAGE_B
#undef STAGE_A2
#undef COMPUTE2

    if (!TRANSP) {
        // epilogue: C/D layout col = lane&15, row = (lane>>4)*4+reg [m89]
#pragma unroll
        for (int j = 0; j < 4; ++j) {
            int col = bx * 256 + wn * 64 + j * 16 + lr;
            float bb = bias[col];
#pragma unroll
            for (int i = 0; i < 8; ++i) {
                int row0 = by * 256 + wm * 128 + i * 16 + kgr * 4;
#pragma unroll
                for (int reg = 0; reg < 4; ++reg)
                    C[(size_t)(row0 + reg) * 1024 + col] = acc[i][j][reg] + bb;
            }
        }
    } else {
        // transposed epilogue: write Qa[bh][e][t]; tile covers t=by*32..+31,
        // all b; h=bx*4..+3, all e. Two col-half passes of 256x128 f32=128KB.
        // XOR swizzle (both sides): cs = c_local ^ (rl>>3 & 31).
        float* lf = (float*)lds;
        const int e_r = (tid >> 3) & 63;
        const int tq = tid & 7;
#pragma unroll
        for (int ch = 0; ch < 2; ++ch) {
            __builtin_amdgcn_s_barrier();   // prev reads of lds done
            if ((wn >> 1) == ch) {
#pragma unroll
                for (int j = 0; j < 4; ++j) {
                    int col = bx * 256 + wn * 64 + j * 16 + lr;
                    float bb = bias[col];
                    int cl = (wn & 1) * 64 + j * 16 + lr;
#pragma unroll
                    for (int i = 0; i < 8; ++i) {
                        int rbase = wm * 128 + i * 16 + kgr * 4;
#pragma unroll
                        for (int reg = 0; reg < 4; ++reg) {
                            int rl = rbase + reg;
                            int cs = cl ^ ((rl >> 3) & 31);
                            lf[rl * 128 + cs] = acc[i][j][reg] + bb;
                        }
                    }
                }
            }
            __syncthreads();
#pragma unroll
            for (int it = 0; it < 16; ++it) {
                int b = it >> 1, hll = it & 1;
                float4 v;
#pragma unroll
                for (int k = 0; k < 4; ++k) {
                    int tl = tq * 4 + k;
                    int rl = tl * 8 + b;
                    int cs = (hll * 64 + e_r) ^ (tl & 31);
                    ((float*)&v)[k] = lf[rl * 128 + cs];
                }
                int bh = b * 16 + bx * 4 + ch * 2 + hll;
                ((float4*)C)[(size_t)(bh * 64 + e_r) * 512 + by * 8 + tq] = v;
            }
        }
    }
}

// ---------------------------------------------------------------------------
// transpose (t,b,d) -> [bh][e][t]   (fallback path only)
// ---------------------------------------------------------------------------
__global__ __launch_bounds__(256)
void transpose_bhet(const float* __restrict__ src, float* __restrict__ dst)
{
    __shared__ float tile[64][129];
    const int tid = threadIdx.x;
    const int bh = blockIdx.x;
    const int b = bh >> 4, h = bh & 15;
    const int t0 = blockIdx.y * 128;
    const float* sp = src + (size_t)(t0 * 8 + b) * 1024 + h * 64;
#pragma unroll
    for (int i = 0; i < 8; ++i) {
        int idx = i * 256 + tid;
        int t = idx >> 4;
        int e4 = (idx & 15) * 4;
        float4 v = *(const float4*)(sp + (size_t)t * 8192 + e4);
        tile[e4 + 0][t] = v.x; tile[e4 + 1][t] = v.y; tile[e4 + 2][t] = v.z; tile[e4 + 3][t] = v.w;
    }
    __syncthreads();
    float* dp = dst + (size_t)bh * 64 * 2048 + t0;
#pragma unroll
    for (int i = 0; i < 8; ++i) {
        int idx = i * 256 + tid;
        int e = idx >> 5;
        int t4 = (idx & 31) * 4;
        float4 o;
        o.x = tile[e][t4]; o.y = tile[e][t4 + 1]; o.z = tile[e][t4 + 2]; o.w = tile[e][t4 + 3];
        *(float4*)(dp + (size_t)e * 2048 + t4) = o;
    }
}

// ---------------------------------------------------------------------------
__device__ __forceinline__ float2 cadd(float2 a, float2 b){ return make_float2(a.x+b.x, a.y+b.y); }
__device__ __forceinline__ float2 csub(float2 a, float2 b){ return make_float2(a.x-b.x, a.y-b.y); }
__device__ __forceinline__ float2 cmul(float2 a, float2 b){ return make_float2(a.x*b.x - a.y*b.y, a.x*b.y + a.y*b.x); }

// ---------------------------------------------------------------------------
// XOR bank-swizzle for the FFT LDS buffers (bijective on [0,2048)).
// ---------------------------------------------------------------------------
__device__ __forceinline__ int swz(int i) { return i ^ ((i >> 4) & 15); }

// ---------------------------------------------------------------------------
// In-LDS 2048-pt complex FFT: 3 radix-8 Stockham stages + 1 twiddle-free
// radix-4 = 4 LDS passes. (See round 9 derivation.)
// ---------------------------------------------------------------------------
__device__ float2* fft2048(float2* x, float2* y, const float2* tw, int tid)
{
#pragma unroll 1
    for (int st = 0; st < 3; ++st) {
        const int s = 1 << (3 * st);   // 1, 8, 64
        const int u = tid;             // 256 butterflies, 1/thread
        const int q = u & (s - 1);
        const int ps = u - q;
        float2 a = x[swz(u)],        e = x[swz(u + 256)];
        float2 b = x[swz(u + 512)],  f = x[swz(u + 768)];
        float2 c = x[swz(u + 1024)], g = x[swz(u + 1280)];
        float2 d = x[swz(u + 1536)], h = x[swz(u + 1792)];
        float2 t0 = cadd(a, c), t1 = csub(a, c);
        float2 t2 = cadd(b, d), tb = csub(b, d);
        float2 t3 = make_float2(tb.y, -tb.x);
        float2 A0 = cadd(t0, t2);
        float2 A1 = cmul(cadd(t1, t3), tw[ps]);
        float2 A2 = cmul(csub(t0, t2), tw[2 * ps]);
        float2 A3 = cmul(csub(t1, t3), tw[3 * ps]);
        float2 s0 = cadd(e, g), s1 = csub(e, g);
        float2 s2 = cadd(f, h), sb = csub(f, h);
        float2 s3 = make_float2(sb.y, -sb.x);
        float2 B0 = cadd(s0, s2);
        float2 B1 = cmul(cadd(s1, s3), tw[ps + 256]);
        float2 B2 = cmul(csub(s0, s2), tw[2 * ps + 512]);
        const int i3 = 3 * ps + 768;
        float2 w3b = (i3 < 1024) ? tw[i3]
                   : make_float2(-tw[i3 - 1024].x, -tw[i3 - 1024].y);
        float2 B3 = cmul(csub(s1, s3), w3b);
        float2 w4 = tw[4 * ps];
        const int o = 8 * ps + q;
        y[swz(o)]         = cadd(A0, B0);
        y[swz(o + s)]     = cadd(A1, B1);
        y[swz(o + 2 * s)] = cadd(A2, B2);
        y[swz(o + 3 * s)] = cadd(A3, B3);
        y[swz(o + 4 * s)] = cmul(csub(A0, B0), w4);
        y[swz(o + 5 * s)] = cmul(csub(A1, B1), w4);
        y[swz(o + 6 * s)] = cmul(csub(A2, B2), w4);
        y[swz(o + 7 * s)] = cmul(csub(A3, B3), w4);
        __syncthreads();
        float2* tsw = x; x = y; y = tsw;
    }
    // final radix-4, s=512: ps==0 -> twiddle-free
#pragma unroll
    for (int ui = 0; ui < 2; ++ui) {
        const int u = ui * 256 + tid;   // [0,512)
        float2 a = x[swz(u)],        b = x[swz(u + 512)];
        float2 c = x[swz(u + 1024)], d = x[swz(u + 1536)];
        float2 t0 = cadd(a, c), t1 = csub(a, c);
        float2 t2 = cadd(b, d), tb = csub(b, d);
        float2 t3 = make_float2(tb.y, -tb.x);
        y[swz(u)]        = cadd(t0, t2);
        y[swz(u + 512)]  = cadd(t1, t3);
        y[swz(u + 1024)] = csub(t0, t2);
        y[swz(u + 1536)] = csub(t1, t3);
    }
    __syncthreads();
    return y;
}

// ---------------------------------------------------------------------------
// corr_fwd: grid (128 bh, 8 eg). FFT 8 packed (Q,K) rows, accumulate partial
// S[f] = sum_e Qf*conj(Kf) in registers, write to Spart[bh][eg][1025].
// ---------------------------------------------------------------------------
__global__ __launch_bounds__(256)
void corr_fwd(const float* __restrict__ Qa, const float* __restrict__ Ka,
              float2* __restrict__ Spart)
{
    __shared__ float2 za[2048];
    __shared__ float2 zb[2048];
    __shared__ float2 tw[1024];
    const int tid = threadIdx.x;
    const int bh = blockIdx.x;
    const int eg = blockIdx.y;

#pragma unroll
    for (int r = 0; r < 4; ++r) {
        int u = tid + 256 * r;
        float sn, cs;
        sincospif((float)u * (1.0f / 1024.0f), &sn, &cs);
        tw[u] = make_float2(cs, -sn);
    }

    float2 sacc[4];
#pragma unroll
    for (int r = 0; r < 4; ++r) sacc[r] = make_float2(0.f, 0.f);
    float2 sacc1024 = make_float2(0.f, 0.f);

    const float* q0 = Qa + ((size_t)bh * 64 + eg * 8) * 2048;
    const float* k0 = Ka + ((size_t)bh * 64 + eg * 8) * 2048;

    for (int e = 0; e < 8; ++e) {
        const float* qr = q0 + (size_t)e * 2048;
        const float* kr = k0 + (size_t)e * 2048;
        for (int t = tid; t < 2048; t += 256)
            za[swz(t)] = make_float2(qr[t], kr[t]);
        __syncthreads();

        float2* res = fft2048(za, zb, tw, tid);

#pragma unroll
        for (int r = 0; r < 4; ++r) {
            int f = tid + 256 * r;
            float2 A  = res[swz(f)];
            float2 Bc = res[swz((2048 - f) & 2047)];
            float Ur = A.x + Bc.x, Ui = A.y - Bc.y;
            float Vr = A.x - Bc.x, Vi = -A.y - Bc.y;
            sacc[r].x += 0.25f * (-(Ur * Vi + Ui * Vr));
            sacc[r].y += 0.25f * ( Ur * Vr - Ui * Vi );
        }
        if (tid == 0) {
            float2 A = res[swz(1024)];
            float Ur = 2.f * A.x;
            float Vi = -2.f * A.y;
            sacc1024.x += 0.25f * (-(Ur * Vi));
            sacc1024.y += 0.25f * 0.f;
        }
        __syncthreads();
    }
    float2* sp = Spart + ((size_t)bh * 8 + eg) * 1025;
#pragma unroll
    for (int r = 0; r < 4; ++r) sp[tid + 256 * r] = sacc[r];
    if (tid == 0) sp[1024] = sacc1024;
}

// ---------------------------------------------------------------------------
// corr_inv_topk: sum 8 partials, inverse FFT (conj trick), top-7 + softmax.
// ---------------------------------------------------------------------------
__global__ __launch_bounds__(256)
void corr_inv_topk(const float2* __restrict__ Spart,
                   int* __restrict__ taus, float* __restrict__ wout)
{
    __shared__ float2 za[2048];
    __shared__ float2 zb[2048];
    __shared__ float2 tw[1024];
    __shared__ float2 Sh[1025];
    __shared__ float  redv[256];
    __shared__ int    redi[256];
    __shared__ float  sc[TOPK];
    __shared__ int    si[TOPK];

    const int tid = threadIdx.x;
    const int bh = blockIdx.x;

#pragma unroll
    for (int r = 0; r < 4; ++r) {
        int u = tid + 256 * r;
        float sn, cs;
        sincospif((float)u * (1.0f / 1024.0f), &sn, &cs);
        tw[u] = make_float2(cs, -sn);
    }

    const float2* sp0 = Spart + (size_t)bh * 8 * 1025;
    for (int f = tid; f < 1025; f += 256) {
        float2 s = make_float2(0.f, 0.f);
#pragma unroll
        for (int g = 0; g < 8; ++g) {
            float2 v = sp0[(size_t)g * 1025 + f];
            s.x += v.x; s.y += v.y;
        }
        Sh[f] = s;
    }
    __syncthreads();
    for (int f = tid; f < 2048; f += 256) {
        float2 v = (f <= 1024) ? make_float2(Sh[f].x, -Sh[f].y) : Sh[2048 - f];
        za[swz(f)] = v;
    }
    __syncthreads();

    float2* res = fft2048(za, zb, tw, tid);

    for (int k = 0; k < TOPK; ++k) {
        float bvv = -INFINITY; int bii = 0;
        for (int t = tid; t < 2048; t += 256) {
            float v = res[swz(t)].x;
            if (v > bvv) { bvv = v; bii = t; }
        }
        redv[tid] = bvv; redi[tid] = bii;
        __syncthreads();
        for (int off = 128; off > 0; off >>= 1) {
            if (tid < off) {
                float ov = redv[tid + off]; int oi = redi[tid + off];
                if (ov > redv[tid] || (ov == redv[tid] && oi < redi[tid])) { redv[tid] = ov; redi[tid] = oi; }
            }
            __syncthreads();
        }
        if (tid == 0) { sc[k] = redv[0]; si[k] = redi[0]; res[swz(redi[0])].x = -INFINITY; }
        __syncthreads();
    }
    if (tid == 0) {
        const float scale = 1.0f / (2048.0f * 64.0f);
        float m = sc[0] * scale;
        float ex[TOPK]; float ssum = 0.f;
        for (int k = 0; k < TOPK; ++k) { ex[k] = expf(sc[k] * scale - m); ssum += ex[k]; }
        for (int k = 0; k < TOPK; ++k) {
            taus[bh * TOPK + k] = si[k];
            wout[bh * TOPK + k] = ex[k] / ssum;
        }
    }
}

// ---------------------------------------------------------------------------
// agg = (1/7) * sum_k w[bh][k] * V[(t+tau_k)%L, b, :]; emits (hi,lo) bf16
// directly (feeds the split-GEMM output projection).
// ---------------------------------------------------------------------------
__global__ __launch_bounds__(256)
void agg_gather(const float* __restrict__ Vp, const int* __restrict__ taus,
                const float* __restrict__ w, ushort* __restrict__ ah,
                ushort* __restrict__ al)
{
    const int tid = threadIdx.x;
    const int bh = blockIdx.x;
    const int b = bh >> 4, h = bh & 15;
    const int t0 = blockIdx.y * 256;
    __shared__ int   stau[TOPK];
    __shared__ float sw[TOPK];
    if (tid < TOPK) { stau[tid] = taus[bh * TOPK + tid]; sw[tid] = w[bh * TOPK + tid] * (1.0f / TOPK); }
    __syncthreads();
    const float* vb = Vp + (size_t)b * 1024 + h * 64;
    ushort* ahb = ah + (size_t)b * 1024 + h * 64;
    ushort* alb = al + (size_t)b * 1024 + h * 64;
#pragma unroll
    for (int i = 0; i < 16; ++i) {
        int idx = i * 256 + tid;
        int t  = t0 + (idx >> 4);
        int e4 = (idx & 15) * 4;
        float a0 = 0.f, a1 = 0.f, a2 = 0.f, a3 = 0.f;
#pragma unroll
        for (int k = 0; k < TOPK; ++k) {
            int ts = (t + stau[k]) & 2047;
            float4 v = *(const float4*)(vb + (size_t)ts * 8192 + e4);
            a0 = fmaf(sw[k], v.x, a0); a1 = fmaf(sw[k], v.y, a1);
            a2 = fmaf(sw[k], v.z, a2); a3 = fmaf(sw[k], v.w, a3);
        }
        ushort4 hh, ll;
        split1(a0, hh.x, ll.x); split1(a1, hh.y, ll.y);
        split1(a2, hh.z, ll.z); split1(a3, hh.w, ll.w);
        *(ushort4*)(ahb + (size_t)t * 8192 + e4) = hh;
        *(ushort4*)(alb + (size_t)t * 8192 + e4) = ll;
    }
}

// ---------------------------------------------------------------------------
extern "C" void kernel_launch(void* const* d_in, const int* in_sizes, int n_in,
                              void* d_out, int out_size, void* d_ws, size_t ws_size,
                              hipStream_t stream)
{
    (void)in_sizes; (void)n_in; (void)out_size;
    const float* query = (const float*)d_in[0];
    const float* key   = (const float*)d_in[1];
    const float* value = (const float*)d_in[2];
    const float* Wq = (const float*)d_in[3];
    const float* bq = (const float*)d_in[4];
    const float* Wk = (const float*)d_in[5];
    const float* bk = (const float*)d_in[6];
    const float* Wv = (const float*)d_in[7];
    const float* bv = (const float*)d_in[8];
    const float* Wo = (const float*)d_in[9];
    const float* bo = (const float*)d_in[10];
    float* out = (float*)d_out;

    const size_t NEL  = (size_t)16777216;   // 16384*1024
    const size_t HEL  = NEL / 2;            // value half
    const size_t WEL  = (size_t)1048576;    // 1024*1024
    const size_t SLOTB = (size_t)64 * 1024 * 1024;
    const size_t MB = (size_t)1024 * 1024;

    char* ws = (char*)d_ws;
    float*  s1 = (float*)ws;                 // fp32 proj outputs (Vp)
    char*   s2 = ws + SLOTB;                 // X(q) -> X(k) -> X(v) -> Spart
    char*   s3 = ws + 2 * SLOTB;             // Qa -> agg hi/lo
    char*   tail = ws + 3 * SLOTB;           // dtaus/dw + W homes
    int*    dtaus = (int*)tail;
    float*  dw    = (float*)(dtaus + 128 * TOPK);
    const bool big_ws = ws_size >= 3 * SLOTB + (size_t)16 * MB;

    dim3 blk(256);
    dim3 gblk(512);
    dim3 gemm_full(4, 64), gemm_half(4, 32);   // 256x256 tiles
    dim3 tr_grid(128, 16);

    if (big_ws) {
        ushort* wqh = (ushort*)d_out;
        ushort* wkh = (ushort*)(tail + 4 * MB);
        ushort* wvh = (ushort*)(tail + 8 * MB);
        ushort* woh = (ushort*)(tail + 12 * MB);

        // 1. all four weight splits in ONE launch
        wsplit4<<<4096, blk, 0, stream>>>(Wq, Wk, Wv, Wo, wqh, wkh, wvh, woh);
        // 2. query split -> s2 (bf16 hi/lo)
        split_f32<<<2048, blk, 0, stream>>>(query, (ushort*)s2, (ushort*)s2 + NEL, (int)(NEL / 4));
        // 3. Q projection + fused transpose -> Qa in s3
        gemm_split<true><<<gemm_full, gblk, 0, stream>>>((ushort*)s2, (ushort*)s2 + NEL,
                                                         wqh, wqh + WEL, bq, (float*)s3);
        // 4. key split -> s2 (query split dead)
        split_f32<<<2048, blk, 0, stream>>>(key, (ushort*)s2, (ushort*)s2 + NEL, (int)(NEL / 4));
        // 5. K projection + fused transpose -> Ka in d_out (Wq home dead)
        float* Ka = (float*)d_out;
        gemm_split<true><<<gemm_full, gblk, 0, stream>>>((ushort*)s2, (ushort*)s2 + NEL,
                                                         wkh, wkh + WEL, bk, Ka);
        // 6. value split -> s2 (key split dead)
        split_f32<<<2048, blk, 0, stream>>>(value, (ushort*)s2, (ushort*)s2 + NEL, (int)(NEL / 4));
        // 7. V projection -> s1 (normal layout, full grid)
        gemm_split<false><<<gemm_full, gblk, 0, stream>>>((ushort*)s2, (ushort*)s2 + NEL,
                                                          wvh, wvh + WEL, bv, s1);
        // 8. correlation forward (Qa=s3, Ka=d_out) -> Spart in s2 (value split dead)
        float2* Spart = (float2*)s2;
        corr_fwd<<<dim3(128, 8), blk, 0, stream>>>((const float*)s3, Ka, Spart);
        // 9. inverse + top-k + softmax
        corr_inv_topk<<<dim3(128), blk, 0, stream>>>(Spart, dtaus, dw);
        // 10. delayed-V aggregation -> (hi,lo) in s3 (Qa dead)
        agg_gather<<<dim3(128, 8), blk, 0, stream>>>(s1, dtaus, dw,
                                                     (ushort*)s3, (ushort*)s3 + NEL);
        // 11. output projection -> d_out
        gemm_split<false><<<gemm_full, gblk, 0, stream>>>((ushort*)s3, (ushort*)s3 + NEL,
                                                          woh, woh + WEL, bo, out);
    } else {
        // fallback: scattered W splits, two-half V path, separate transposes
        split_f32<<<1024, blk, 0, stream>>>(Wq, (ushort*)s3, (ushort*)s3 + WEL, (int)(WEL / 4));
        split_f32<<<2048, blk, 0, stream>>>(query, (ushort*)s2, (ushort*)s2 + NEL, (int)(NEL / 4));
        gemm_split<false><<<gemm_full, gblk, 0, stream>>>((ushort*)s2, (ushort*)s2 + NEL,
                                                          (ushort*)s3, (ushort*)s3 + WEL, bq, s1);
        transpose_bhet<<<tr_grid, blk, 0, stream>>>(s1, (float*)s2);
        ushort* wkh = (ushort*)d_out;
        split_f32<<<1024, blk, 0, stream>>>(Wk, wkh, wkh + WEL, (int)(WEL / 4));
        split_f32<<<2048, blk, 0, stream>>>(key, (ushort*)s3, (ushort*)s3 + NEL, (int)(NEL / 4));
        gemm_split<false><<<gemm_full, gblk, 0, stream>>>((ushort*)s3, (ushort*)s3 + NEL,
                                                          wkh, wkh + WEL, bk, s1);
        transpose_bhet<<<tr_grid, blk, 0, stream>>>(s1, (float*)s3);
        ushort* wvh = (ushort*)((char*)d_out + (size_t)32 * MB);
        split_f32<<<1024, blk, 0, stream>>>(Wv, wvh, wvh + WEL, (int)(WEL / 4));
        ushort* vsp = (ushort*)d_out;
        for (int hhalf = 0; hhalf < 2; ++hhalf) {
            split_f32<<<2048, blk, 0, stream>>>(value + hhalf * HEL, vsp, vsp + HEL, (int)(HEL / 4));
            gemm_split<false><<<gemm_half, gblk, 0, stream>>>(vsp, vsp + HEL, wvh, wvh + WEL,
                                                              bv, s1 + hhalf * HEL);
        }
        float2* Spart = (float2*)d_out;
        corr_fwd<<<dim3(128, 8), blk, 0, stream>>>((const float*)s2, (const float*)s3, Spart);
        corr_inv_topk<<<dim3(128), blk, 0, stream>>>(Spart, dtaus, dw);
        agg_gather<<<dim3(128, 8), blk, 0, stream>>>(s1, dtaus, dw,
                                                     (ushort*)s2, (ushort*)s2 + NEL);
        split_f32<<<1024, blk, 0, stream>>>(Wo, (ushort*)s3, (ushort*)s3 + WEL, (int)(WEL / 4));
        gemm_split<false><<<gemm_full, gblk, 0, stream>>>((ushort*)s2, (ushort*)s2 + NEL,
                                                          (ushort*)s3, (ushort*)s3 + WEL, bo, out);
    }
}